// Round 1
// baseline (327.551 us; speedup 1.0000x reference)
//
#include <hip/hip_runtime.h>
#include <hip/hip_bf16.h>

typedef __hip_bfloat16 bf16;
typedef __attribute__((ext_vector_type(8))) short bf16x8;   // 8 bf16 = 4 VGPRs (MFMA A/B frag)
typedef __attribute__((ext_vector_type(4))) float f32x4;    // MFMA C/D frag

typedef const __attribute__((address_space(1))) unsigned int* gp_t;
typedef __attribute__((address_space(3))) unsigned int* lp_t;

__device__ __forceinline__ bf16 tobf(float f) { return __float2bfloat16(f); }
__device__ __forceinline__ float tof(bf16 h) { return __bfloat162float(h); }

__device__ __forceinline__ void gload_lds16(const void* g, void* l) {
    // 16B per lane, dest = wave-uniform LDS base + lane*16
    __builtin_amdgcn_global_load_lds((gp_t)g, (lp_t)l, 16, 0, 0);
}

// ---------------------------------------------------------------------------
// Weight fp32 -> bf16 (4 matrices of 1M elements each, contiguous dst)
// ---------------------------------------------------------------------------
__global__ __launch_bounds__(256) void convert_w(const float* qw, const float* kw,
                                                 const float* vw, const float* pw,
                                                 bf16* dst) {
    int m = blockIdx.y;
    const float* src = m == 0 ? qw : (m == 1 ? kw : (m == 2 ? vw : pw));
    bf16* d = dst + (size_t)m * (1u << 20);
    int i = (blockIdx.x * 256 + threadIdx.x) * 4;
    float4 f = *(const float4*)(src + i);
    d[i + 0] = tobf(f.x);
    d[i + 1] = tobf(f.y);
    d[i + 2] = tobf(f.z);
    d[i + 3] = tobf(f.w);
}

// ---------------------------------------------------------------------------
// LoRA gate: xq = x + (x_prev - x) * (lam + tanh(x@a.T)@b.T), bf16 out.
// 8 rows (t) per block to amortize the b-matrix reads.
// ---------------------------------------------------------------------------
__global__ __launch_bounds__(256) void lora_gate(
    const float* x,
    const float* qa, const float* qbw, const float* ql,
    const float* ka, const float* kbw, const float* kl,
    const float* va, const float* vbw, const float* vl,
    bf16* xqo, bf16* xko, bf16* xvo) {
    int row0 = blockIdx.x * 8;   // b*T + t, 8 consecutive t (never crosses batch)
    int t0 = row0 & 1023;
    int tid = threadIdx.x;
    __shared__ float sx[8][1024];
    __shared__ float st[8][48];
    for (int i = tid; i < 8 * 1024; i += 256)
        ((float*)sx)[i] = x[(size_t)row0 * 1024 + i];
    __syncthreads();
    int wave = tid >> 6, lane = tid & 63;
    for (int r = wave; r < 48; r += 4) {
        const float* arow = r < 16 ? qa + r * 1024
                                   : (r < 32 ? ka + (r - 16) * 1024 : va + (r - 32) * 1024);
        float a[16];
#pragma unroll
        for (int i = 0; i < 16; i++) a[i] = arow[lane + i * 64];
#pragma unroll
        for (int rr = 0; rr < 8; ++rr) {
            float s = 0.f;
#pragma unroll
            for (int i = 0; i < 16; i++) s += a[i] * sx[rr][lane + i * 64];
#pragma unroll
            for (int off = 32; off; off >>= 1) s += __shfl_down(s, off);
            if (lane == 0) st[rr][r] = tanhf(s);
        }
    }
    __syncthreads();
    for (int d = tid; d < 1024; d += 256) {
        float qbv[16], kbv[16], vbv[16];
#pragma unroll
        for (int j = 0; j < 16; j++) {
            qbv[j] = qbw[d * 16 + j];
            kbv[j] = kbw[d * 16 + j];
            vbv[j] = vbw[d * 16 + j];
        }
        float qlv = ql[d], klv = kl[d], vlv = vl[d];
#pragma unroll
        for (int rr = 0; rr < 8; ++rr) {
            int row = row0 + rr;
            float xc = sx[rr][d];
            float xp;
            if (rr == 0)
                xp = (t0 == 0) ? 0.f : x[(size_t)(row - 1) * 1024 + d];
            else
                xp = sx[rr - 1][d];
            float dx = xp - xc;
            float gq = qlv, gk = klv, gv = vlv;
#pragma unroll
            for (int j = 0; j < 16; j++) {
                gq += st[rr][j] * qbv[j];
                gk += st[rr][16 + j] * kbv[j];
                gv += st[rr][32 + j] * vbv[j];
            }
            xqo[(size_t)row * 1024 + d] = tobf(xc + dx * gq);
            xko[(size_t)row * 1024 + d] = tobf(xc + dx * gk);
            xvo[(size_t)row * 1024 + d] = tobf(xc + dx * gv);
        }
    }
}

// ---------------------------------------------------------------------------
// m97-style bf16 GEMM: C[m,n] = sum_k A[m,k]*W[n,k] (+bias). K=1024, 128x128 tile.
// mode proj=0: z selects (A,W,C) of q/k/v, bf16 out. proj=1: fp32 out + bias.
// ---------------------------------------------------------------------------
__global__ __launch_bounds__(256) void gemm128(
    const bf16* A0, const bf16* A1, const bf16* A2,
    const bf16* W0, const bf16* W1, const bf16* W2,
    bf16* C0, bf16* C1, bf16* C2,
    const float* bias, float* outF, int proj) {
    const int K = 1024;
    int bz = blockIdx.z;
    const bf16* A = bz == 0 ? A0 : (bz == 1 ? A1 : A2);
    const bf16* W = bz == 0 ? W0 : (bz == 1 ? W1 : W2);
    bf16* C = bz == 0 ? C0 : (bz == 1 ? C1 : C2);
    int m0 = blockIdx.y * 128, n0 = blockIdx.x * 128;

    __shared__ alignas(16) bf16 sA[128 * 32];
    __shared__ alignas(16) bf16 sB[128 * 32];

    int wave = threadIdx.x >> 6, lane = threadIdx.x & 63;
    int quad = lane >> 4, l16 = lane & 15;

    f32x4 acc[4][4];
#pragma unroll
    for (int i = 0; i < 4; i++)
#pragma unroll
        for (int j = 0; j < 4; j++) acc[i][j] = (f32x4){0.f, 0.f, 0.f, 0.f};

    int srow = wave * 16 + (lane >> 2);   // staging row within 64-row pass
    int scol = (lane & 3) * 8;            // staging col (elements)

    for (int k0 = 0; k0 < K; k0 += 32) {
        __syncthreads();
#pragma unroll
        for (int p = 0; p < 2; p++) {
            int row = p * 64 + srow;
            gload_lds16(A + (size_t)(m0 + row) * K + k0 + scol, &sA[(p * 64 + wave * 16) * 32]);
            gload_lds16(W + (size_t)(n0 + row) * K + k0 + scol, &sB[(p * 64 + wave * 16) * 32]);
        }
        __syncthreads();
        int mw = (wave >> 1) * 64, nw = (wave & 1) * 64;
        bf16x8 af[4], bfr[4];
#pragma unroll
        for (int f = 0; f < 4; f++) {
            af[f] = *(const bf16x8*)&sA[(mw + f * 16 + l16) * 32 + quad * 8];
            bfr[f] = *(const bf16x8*)&sB[(nw + f * 16 + l16) * 32 + quad * 8];
        }
#pragma unroll
        for (int i = 0; i < 4; i++)
#pragma unroll
            for (int j = 0; j < 4; j++)
                acc[i][j] = __builtin_amdgcn_mfma_f32_16x16x32_bf16(af[i], bfr[j], acc[i][j], 0, 0, 0);
    }

    int mw = (wave >> 1) * 64, nw = (wave & 1) * 64;
#pragma unroll
    for (int i = 0; i < 4; i++) {
        int mrow = m0 + mw + i * 16 + quad * 4;
#pragma unroll
        for (int j = 0; j < 4; j++) {
            int col = n0 + nw + j * 16 + l16;
            if (proj) {
                float bv = bias[col];
#pragma unroll
                for (int r = 0; r < 4; r++)
                    outF[(size_t)(mrow + r) * 1024 + col] = acc[i][j][r] + bv;
            } else {
#pragma unroll
                for (int r = 0; r < 4; r++)
                    C[(size_t)(mrow + r) * 1024 + col] = tobf(acc[i][j][r]);
            }
        }
    }
}

// ---------------------------------------------------------------------------
// RoPE (q,k) + head-split layout, V transpose. Per block: one (b,h), 64 t-rows.
// Qh,Kh: [bh][t][64] bf16 (Q pre-scaled by 0.125). Vt: [bh][d][T=1024] bf16.
// ---------------------------------------------------------------------------
__global__ __launch_bounds__(256) void rope_transform(
    const bf16* q, const bf16* k, const bf16* v,
    bf16* Qh, bf16* Kh, bf16* Vt) {
    int bh = blockIdx.x, tblk = blockIdx.y;
    int b = bh >> 4, h = bh & 15;
    int t0 = tblk * 64;
    int tid = threadIdx.x;

    int i0 = (tid & 7) * 4;   // rotary index base (0..28)
#pragma unroll
    for (int pp = 0; pp < 2; ++pp) {
        int t = t0 + pp * 32 + (tid >> 3);
        size_t gin = ((size_t)(b * 1024 + t)) * 1024 + h * 64;
        size_t gout = ((size_t)(bh * 1024 + t)) * 64;
        float c[4], s[4];
#pragma unroll
        for (int u = 0; u < 4; ++u) {
            int i = i0 + u;
            float theta = __expf(-(float)i * (9.210340371976184f / 32.0f)); // 10000^(-i/32)
            sincosf((float)t * theta, &s[u], &c[u]);
        }
        float xr[4], xi[4];
#pragma unroll
        for (int u = 0; u < 4; u++) { xr[u] = tof(q[gin + i0 + u]); xi[u] = tof(q[gin + 32 + i0 + u]); }
#pragma unroll
        for (int u = 0; u < 4; u++) {
            Qh[gout + i0 + u]      = tobf((xr[u] * c[u] - xi[u] * s[u]) * 0.125f);
            Qh[gout + 32 + i0 + u] = tobf((xr[u] * s[u] + xi[u] * c[u]) * 0.125f);
        }
#pragma unroll
        for (int u = 0; u < 4; u++) { xr[u] = tof(k[gin + i0 + u]); xi[u] = tof(k[gin + 32 + i0 + u]); }
#pragma unroll
        for (int u = 0; u < 4; u++) {
            Kh[gout + i0 + u]      = tobf(xr[u] * c[u] - xi[u] * s[u]);
            Kh[gout + 32 + i0 + u] = tobf(xr[u] * s[u] + xi[u] * c[u]);
        }
    }

    __shared__ bf16 sv[64 * 65];
    {
        int r = tid >> 2;
        int c0 = (tid & 3) * 16;
        size_t g = ((size_t)(b * 1024 + t0 + r)) * 1024 + h * 64 + c0;
#pragma unroll
        for (int u = 0; u < 16; u++) sv[(c0 + u) * 65 + r] = v[g + u];
    }
    __syncthreads();
    {
        int d = tid >> 2;
        int tc = (tid & 3) * 16;
        size_t g = ((size_t)(bh * 64 + d)) * 1024 + t0 + tc;
#pragma unroll
        for (int u = 0; u < 16; u++) Vt[g + u] = sv[d * 65 + tc + u];
    }
}

// ---------------------------------------------------------------------------
// Causal flash attention. Block = 64 q-rows (4 waves x 16), 64-key tiles.
// Q pre-scaled by 1/8. Writes attn merged-head layout [b*T+t][h*64+d] bf16.
// ---------------------------------------------------------------------------
__global__ __launch_bounds__(256) void attention(const bf16* Qh, const bf16* Kh,
                                                 const bf16* Vt, bf16* attn) {
    int qblk = blockIdx.x;   // 0..15
    int bh = blockIdx.y;     // 0..63
    int b = bh >> 4, h = bh & 15;
    int wave = threadIdx.x >> 6, lane = threadIdx.x & 63;
    int quad = lane >> 4, l16 = lane & 15;

    const bf16* Qb = Qh + (size_t)bh * 1024 * 64;
    const bf16* Kb = Kh + (size_t)bh * 1024 * 64;
    const bf16* Vb = Vt + (size_t)bh * 64 * 1024;

    __shared__ alignas(16) bf16 sK[64 * 64];
    __shared__ alignas(16) bf16 sV[64 * 64];   // sV[d][key] (transposed V tile)
    __shared__ alignas(16) bf16 sP[4][16 * 64];

    int qrow0 = qblk * 64 + wave * 16;
    bf16x8 aq0 = *(const bf16x8*)&Qb[(size_t)(qrow0 + l16) * 64 + quad * 8];
    bf16x8 aq1 = *(const bf16x8*)&Qb[(size_t)(qrow0 + l16) * 64 + quad * 8 + 32];

    f32x4 o[4];
#pragma unroll
    for (int nt = 0; nt < 4; nt++) o[nt] = (f32x4){0.f, 0.f, 0.f, 0.f};
    float mrow[4], lrow[4];
#pragma unroll
    for (int r = 0; r < 4; r++) { mrow[r] = -3.0e38f; lrow[r] = 0.f; }

    for (int kt = 0; kt <= qblk; ++kt) {
        __syncthreads();
#pragma unroll
        for (int p = 0; p < 2; p++) {
            int rbase = p * 32 + wave * 8;   // 8 rows per wave per pass (128B rows)
            gload_lds16(Kb + (size_t)(kt * 64 + rbase + (lane >> 3)) * 64 + (lane & 7) * 8,
                        &sK[rbase * 64]);
            gload_lds16(Vb + (size_t)(rbase + (lane >> 3)) * 1024 + kt * 64 + (lane & 7) * 8,
                        &sV[rbase * 64]);
        }
        __syncthreads();

        f32x4 S[4];
#pragma unroll
        for (int j = 0; j < 4; j++) {
            bf16x8 bk0 = *(const bf16x8*)&sK[(j * 16 + l16) * 64 + quad * 8];
            bf16x8 bk1 = *(const bf16x8*)&sK[(j * 16 + l16) * 64 + quad * 8 + 32];
            f32x4 z = __builtin_amdgcn_mfma_f32_16x16x32_bf16(aq0, bk0, (f32x4){0.f, 0.f, 0.f, 0.f}, 0, 0, 0);
            S[j] = __builtin_amdgcn_mfma_f32_16x16x32_bf16(aq1, bk1, z, 0, 0, 0);
        }
        if (kt == qblk) {   // diagonal tile: mask key > query
#pragma unroll
            for (int j = 0; j < 4; j++) {
                int key = kt * 64 + j * 16 + l16;
#pragma unroll
                for (int r = 0; r < 4; r++) {
                    int qr = qrow0 + quad * 4 + r;
                    if (key > qr) S[j][r] = -3.0e38f;
                }
            }
        }
        // online softmax (rows live in 16-lane groups sharing `quad`)
        float alpha[4];
#pragma unroll
        for (int r = 0; r < 4; r++) {
            float vmax = fmaxf(fmaxf(S[0][r], S[1][r]), fmaxf(S[2][r], S[3][r]));
            vmax = fmaxf(vmax, __shfl_xor(vmax, 1));
            vmax = fmaxf(vmax, __shfl_xor(vmax, 2));
            vmax = fmaxf(vmax, __shfl_xor(vmax, 4));
            vmax = fmaxf(vmax, __shfl_xor(vmax, 8));
            float mn = fmaxf(mrow[r], vmax);
            alpha[r] = __expf(mrow[r] - mn);
            mrow[r] = mn;
        }
        float rs[4] = {0.f, 0.f, 0.f, 0.f};
#pragma unroll
        for (int j = 0; j < 4; j++)
#pragma unroll
            for (int r = 0; r < 4; r++) {
                float p = __expf(S[j][r] - mrow[r]);
                S[j][r] = p;
                rs[r] += p;
            }
#pragma unroll
        for (int r = 0; r < 4; r++) {
            float v = rs[r];
            v += __shfl_xor(v, 1);
            v += __shfl_xor(v, 2);
            v += __shfl_xor(v, 4);
            v += __shfl_xor(v, 8);
            lrow[r] = lrow[r] * alpha[r] + v;
        }
#pragma unroll
        for (int nt = 0; nt < 4; nt++)
#pragma unroll
            for (int r = 0; r < 4; r++) o[nt][r] *= alpha[r];

        // P: C-layout -> A-layout via per-wave LDS round trip (wave-local, no barrier)
#pragma unroll
        for (int j = 0; j < 4; j++)
#pragma unroll
            for (int r = 0; r < 4; r++)
                sP[wave][(quad * 4 + r) * 64 + j * 16 + l16] = tobf(S[j][r]);
        asm volatile("s_waitcnt lgkmcnt(0)" ::: "memory");
        bf16x8 ap0 = *(const bf16x8*)&sP[wave][l16 * 64 + quad * 8];
        bf16x8 ap1 = *(const bf16x8*)&sP[wave][l16 * 64 + quad * 8 + 32];
#pragma unroll
        for (int nt = 0; nt < 4; nt++) {
            bf16x8 bv0 = *(const bf16x8*)&sV[(nt * 16 + l16) * 64 + quad * 8];
            bf16x8 bv1 = *(const bf16x8*)&sV[(nt * 16 + l16) * 64 + quad * 8 + 32];
            o[nt] = __builtin_amdgcn_mfma_f32_16x16x32_bf16(ap0, bv0, o[nt], 0, 0, 0);
            o[nt] = __builtin_amdgcn_mfma_f32_16x16x32_bf16(ap1, bv1, o[nt], 0, 0, 0);
        }
    }

    float invl[4];
#pragma unroll
    for (int r = 0; r < 4; r++) invl[r] = 1.0f / lrow[r];
#pragma unroll
    for (int nt = 0; nt < 4; nt++)
#pragma unroll
        for (int r = 0; r < 4; r++) {
            int t = qrow0 + quad * 4 + r;
            int col = h * 64 + nt * 16 + l16;
            attn[(size_t)(b * 1024 + t) * 1024 + col] = tobf(o[nt][r] * invl[r]);
        }
}

// ---------------------------------------------------------------------------
extern "C" void kernel_launch(void* const* d_in, const int* in_sizes, int n_in,
                              void* d_out, int out_size, void* d_ws, size_t ws_size,
                              hipStream_t stream) {
    const float* x = (const float*)d_in[0];
    const float* qw = (const float*)d_in[1];
    const float* kw = (const float*)d_in[2];
    const float* vw = (const float*)d_in[3];
    const float* qa = (const float*)d_in[4];
    const float* qb = (const float*)d_in[5];
    const float* ql = (const float*)d_in[6];
    const float* ka = (const float*)d_in[7];
    const float* kb = (const float*)d_in[8];
    const float* kl = (const float*)d_in[9];
    const float* va = (const float*)d_in[10];
    const float* vb = (const float*)d_in[11];
    const float* vl = (const float*)d_in[12];
    const float* pw = (const float*)d_in[13];
    const float* pb = (const float*)d_in[14];
    float* out = (float*)d_out;

    char* ws = (char*)d_ws;
    const size_t MB = 1024 * 1024;
    bf16* wqb = (bf16*)ws;                  // [0,8MB): 4 weight matrices bf16
    bf16* wkb = wqb + 1048576;
    bf16* wvb = wkb + 1048576;
    bf16* wpb = wvb + 1048576;
    bf16* xqb = (bf16*)(ws + 8 * MB);       // [8,32MB): gated inputs
    bf16* xkb = xqb + 4194304;
    bf16* xvb = xkb + 4194304;
    bf16* qm = (bf16*)(ws + 32 * MB);       // [32,56MB): q,k,v GEMM outputs
    bf16* km = qm + 4194304;
    bf16* vm = km + 4194304;
    // aliases (stream-ordered reuse of dead buffers)
    bf16* Qh = xqb;    // rope_transform consumes qm/km/vm, xq* is dead
    bf16* Kh = xkb;
    bf16* Vt = xvb;
    bf16* attn = qm;   // attention consumes Qh/Kh/Vt, qm is dead

    convert_w<<<dim3(1024, 4), 256, 0, stream>>>(qw, kw, vw, pw, wqb);
    lora_gate<<<512, 256, 0, stream>>>(x, qa, qb, ql, ka, kb, kl, va, vb, vl, xqb, xkb, xvb);
    gemm128<<<dim3(8, 32, 3), 256, 0, stream>>>(xqb, xkb, xvb, wqb, wkb, wvb, qm, km, vm,
                                                nullptr, nullptr, 0);
    rope_transform<<<dim3(64, 16), 256, 0, stream>>>(qm, km, vm, Qh, Kh, Vt);
    attention<<<dim3(16, 64), 256, 0, stream>>>(Qh, Kh, Vt, attn);
    gemm128<<<dim3(8, 32, 1), 256, 0, stream>>>(attn, nullptr, nullptr, wpb, nullptr, nullptr,
                                                nullptr, nullptr, nullptr, pb, out, 1);
}

// Round 2
// 323.105 us; speedup vs baseline: 1.0138x; 1.0138x over previous
//
#include <hip/hip_runtime.h>
#include <hip/hip_bf16.h>

typedef __hip_bfloat16 bf16;
typedef __attribute__((ext_vector_type(8))) short bf16x8;   // 8 bf16 = 4 VGPRs (MFMA A/B frag)
typedef __attribute__((ext_vector_type(4))) float f32x4;    // MFMA C/D frag

typedef const __attribute__((address_space(1))) unsigned int* gp_t;
typedef __attribute__((address_space(3))) unsigned int* lp_t;

__device__ __forceinline__ bf16 tobf(float f) { return __float2bfloat16(f); }
__device__ __forceinline__ float tof(bf16 h) { return __bfloat162float(h); }

__device__ __forceinline__ short bfbits(float f) {
    bf16 h = __float2bfloat16(f);
    return *reinterpret_cast<short*>(&h);
}
__device__ __forceinline__ bf16x8 pack8(float4 a, float4 b) {
    bf16x8 r;
    r[0] = bfbits(a.x); r[1] = bfbits(a.y); r[2] = bfbits(a.z); r[3] = bfbits(a.w);
    r[4] = bfbits(b.x); r[5] = bfbits(b.y); r[6] = bfbits(b.z); r[7] = bfbits(b.w);
    return r;
}

__device__ __forceinline__ void gload_lds16(const void* g, void* l) {
    // 16B per lane, dest = wave-uniform LDS base + lane*16
    __builtin_amdgcn_global_load_lds((gp_t)g, (lp_t)l, 16, 0, 0);
}

// ---------------------------------------------------------------------------
// Weight fp32 -> bf16 (4 matrices of 1M elements each, contiguous dst)
// ---------------------------------------------------------------------------
__global__ __launch_bounds__(256) void convert_w(const float* qw, const float* kw,
                                                 const float* vw, const float* pw,
                                                 bf16* dst) {
    int m = blockIdx.y;
    const float* src = m == 0 ? qw : (m == 1 ? kw : (m == 2 ? vw : pw));
    bf16* d = dst + (size_t)m * (1u << 20);
    int i = (blockIdx.x * 256 + threadIdx.x) * 4;
    float4 f = *(const float4*)(src + i);
    d[i + 0] = tobf(f.x);
    d[i + 1] = tobf(f.y);
    d[i + 2] = tobf(f.z);
    d[i + 3] = tobf(f.w);
}

// ---------------------------------------------------------------------------
// lora_t: T[row][48] = tanh(x @ a^T) for q,k,v stacked (cols 0-15 q, 16-31 k,
// 32-47 v). One wave per 16-row M-tile, MFMA 16x16x32, operands straight from
// global with in-register fp32->bf16 pack. a matrices (192 KB) are L2-hot.
// ---------------------------------------------------------------------------
__global__ __launch_bounds__(64) void lora_t(const float* x, const float* qa,
                                             const float* ka, const float* va,
                                             float* T) {
    int m0 = blockIdx.x * 16;
    int lane = threadIdx.x;
    int quad = lane >> 4, l16 = lane & 15;

    f32x4 acc[3];
#pragma unroll
    for (int j = 0; j < 3; j++) acc[j] = (f32x4){0.f, 0.f, 0.f, 0.f};

#pragma unroll 4
    for (int k0 = 0; k0 < 1024; k0 += 32) {
        const float* xs = x + (size_t)(m0 + l16) * 1024 + k0 + quad * 8;
        bf16x8 af = pack8(*(const float4*)xs, *(const float4*)(xs + 4));
#pragma unroll
        for (int j = 0; j < 3; ++j) {
            const float* as = (j == 0 ? qa : (j == 1 ? ka : va)) + (size_t)l16 * 1024 + k0 + quad * 8;
            bf16x8 bf_ = pack8(*(const float4*)as, *(const float4*)(as + 4));
            acc[j] = __builtin_amdgcn_mfma_f32_16x16x32_bf16(af, bf_, acc[j], 0, 0, 0);
        }
    }
#pragma unroll
    for (int j = 0; j < 3; ++j)
#pragma unroll
        for (int r = 0; r < 4; ++r) {
            int row = m0 + quad * 4 + r;       // C-layout: row = quad*4+reg, col = l16
            T[(size_t)row * 48 + j * 16 + l16] = tanhf(acc[j][r]);
        }
}

// ---------------------------------------------------------------------------
// gate: xq/xk/xv[row][d] = x + (x_prev - x) * (lam[d] + dot16(T[row], b[d])).
// Block = 16 rows; thread owns 4 d-columns, b-weights in registers, x_prev
// register-carried across the row walk.
// ---------------------------------------------------------------------------
__global__ __launch_bounds__(256) void gate(
    const float* x, const float* T,
    const float* qbw, const float* ql,
    const float* kbw, const float* kl,
    const float* vbw, const float* vl,
    bf16* xqo, bf16* xko, bf16* xvo) {
    int row0 = blockIdx.x * 16;
    int tid = threadIdx.x;
    __shared__ float sT[16][48];
    if (tid < 768) ((float*)sT)[tid] = T[(size_t)row0 * 48 + tid];
    __syncthreads();

#pragma unroll
    for (int u = 0; u < 4; ++u) {
        int d = tid + u * 256;
        float qbv[16], kbv[16], vbv[16];
#pragma unroll
        for (int p = 0; p < 4; ++p) {
            *(float4*)&qbv[p * 4] = *(const float4*)(qbw + (size_t)d * 16 + p * 4);
            *(float4*)&kbv[p * 4] = *(const float4*)(kbw + (size_t)d * 16 + p * 4);
            *(float4*)&vbv[p * 4] = *(const float4*)(vbw + (size_t)d * 16 + p * 4);
        }
        float qlv = ql[d], klv = kl[d], vlv = vl[d];
        float xp = ((row0 & 1023) == 0) ? 0.f : x[(size_t)(row0 - 1) * 1024 + d];
        for (int rr = 0; rr < 16; ++rr) {
            int row = row0 + rr;
            float xc = x[(size_t)row * 1024 + d];
            float dx = xp - xc;
            float gq = qlv, gk = klv, gv = vlv;
#pragma unroll
            for (int j = 0; j < 16; ++j) {
                gq += sT[rr][j] * qbv[j];
                gk += sT[rr][16 + j] * kbv[j];
                gv += sT[rr][32 + j] * vbv[j];
            }
            size_t o = (size_t)row * 1024 + d;
            xqo[o] = tobf(xc + dx * gq);
            xko[o] = tobf(xc + dx * gk);
            xvo[o] = tobf(xc + dx * gv);
            xp = xc;
        }
    }
}

// ---------------------------------------------------------------------------
// m97-style bf16 GEMM: C[m,n] = sum_k A[m,k]*W[n,k] (+bias). K=1024, 128x128 tile.
// mode proj=0: z selects (A,W,C) of q/k/v, bf16 out. proj=1: fp32 out + bias.
// ---------------------------------------------------------------------------
__global__ __launch_bounds__(256) void gemm128(
    const bf16* A0, const bf16* A1, const bf16* A2,
    const bf16* W0, const bf16* W1, const bf16* W2,
    bf16* C0, bf16* C1, bf16* C2,
    const float* bias, float* outF, int proj) {
    const int K = 1024;
    int bz = blockIdx.z;
    const bf16* A = bz == 0 ? A0 : (bz == 1 ? A1 : A2);
    const bf16* W = bz == 0 ? W0 : (bz == 1 ? W1 : W2);
    bf16* C = bz == 0 ? C0 : (bz == 1 ? C1 : C2);
    int m0 = blockIdx.y * 128, n0 = blockIdx.x * 128;

    __shared__ alignas(16) bf16 sA[128 * 32];
    __shared__ alignas(16) bf16 sB[128 * 32];

    int wave = threadIdx.x >> 6, lane = threadIdx.x & 63;
    int quad = lane >> 4, l16 = lane & 15;

    f32x4 acc[4][4];
#pragma unroll
    for (int i = 0; i < 4; i++)
#pragma unroll
        for (int j = 0; j < 4; j++) acc[i][j] = (f32x4){0.f, 0.f, 0.f, 0.f};

    int srow = wave * 16 + (lane >> 2);   // staging row within 64-row pass
    int scol = (lane & 3) * 8;            // staging col (elements)

    for (int k0 = 0; k0 < K; k0 += 32) {
        __syncthreads();
#pragma unroll
        for (int p = 0; p < 2; p++) {
            int row = p * 64 + srow;
            gload_lds16(A + (size_t)(m0 + row) * K + k0 + scol, &sA[(p * 64 + wave * 16) * 32]);
            gload_lds16(W + (size_t)(n0 + row) * K + k0 + scol, &sB[(p * 64 + wave * 16) * 32]);
        }
        __syncthreads();
        int mw = (wave >> 1) * 64, nw = (wave & 1) * 64;
        bf16x8 af[4], bfr[4];
#pragma unroll
        for (int f = 0; f < 4; f++) {
            af[f] = *(const bf16x8*)&sA[(mw + f * 16 + l16) * 32 + quad * 8];
            bfr[f] = *(const bf16x8*)&sB[(nw + f * 16 + l16) * 32 + quad * 8];
        }
#pragma unroll
        for (int i = 0; i < 4; i++)
#pragma unroll
            for (int j = 0; j < 4; j++)
                acc[i][j] = __builtin_amdgcn_mfma_f32_16x16x32_bf16(af[i], bfr[j], acc[i][j], 0, 0, 0);
    }

    int mw = (wave >> 1) * 64, nw = (wave & 1) * 64;
#pragma unroll
    for (int i = 0; i < 4; i++) {
        int mrow = m0 + mw + i * 16 + quad * 4;
#pragma unroll
        for (int j = 0; j < 4; j++) {
            int col = n0 + nw + j * 16 + l16;
            if (proj) {
                float bv = bias[col];
#pragma unroll
                for (int r = 0; r < 4; r++)
                    outF[(size_t)(mrow + r) * 1024 + col] = acc[i][j][r] + bv;
            } else {
#pragma unroll
                for (int r = 0; r < 4; r++)
                    C[(size_t)(mrow + r) * 1024 + col] = tobf(acc[i][j][r]);
            }
        }
    }
}

// ---------------------------------------------------------------------------
// RoPE (q,k) + head-split layout, V transpose. Per block: one (b,h), 64 t-rows.
// Qh,Kh: [bh][t][64] bf16 (Q pre-scaled by 0.125). Vt: [bh][d][T=1024] bf16.
// ---------------------------------------------------------------------------
__global__ __launch_bounds__(256) void rope_transform(
    const bf16* q, const bf16* k, const bf16* v,
    bf16* Qh, bf16* Kh, bf16* Vt) {
    int bh = blockIdx.x, tblk = blockIdx.y;
    int b = bh >> 4, h = bh & 15;
    int t0 = tblk * 64;
    int tid = threadIdx.x;

    int i0 = (tid & 7) * 4;   // rotary index base (0..28)
#pragma unroll
    for (int pp = 0; pp < 2; ++pp) {
        int t = t0 + pp * 32 + (tid >> 3);
        size_t gin = ((size_t)(b * 1024 + t)) * 1024 + h * 64;
        size_t gout = ((size_t)(bh * 1024 + t)) * 64;
        float c[4], s[4];
#pragma unroll
        for (int u = 0; u < 4; ++u) {
            int i = i0 + u;
            float theta = __expf(-(float)i * (9.210340371976184f / 32.0f)); // 10000^(-i/32)
            sincosf((float)t * theta, &s[u], &c[u]);
        }
        float xr[4], xi[4];
#pragma unroll
        for (int u = 0; u < 4; u++) { xr[u] = tof(q[gin + i0 + u]); xi[u] = tof(q[gin + 32 + i0 + u]); }
#pragma unroll
        for (int u = 0; u < 4; u++) {
            Qh[gout + i0 + u]      = tobf((xr[u] * c[u] - xi[u] * s[u]) * 0.125f);
            Qh[gout + 32 + i0 + u] = tobf((xr[u] * s[u] + xi[u] * c[u]) * 0.125f);
        }
#pragma unroll
        for (int u = 0; u < 4; u++) { xr[u] = tof(k[gin + i0 + u]); xi[u] = tof(k[gin + 32 + i0 + u]); }
#pragma unroll
        for (int u = 0; u < 4; u++) {
            Kh[gout + i0 + u]      = tobf(xr[u] * c[u] - xi[u] * s[u]);
            Kh[gout + 32 + i0 + u] = tobf(xr[u] * s[u] + xi[u] * c[u]);
        }
    }

    __shared__ bf16 sv[64 * 65];
    {
        int r = tid >> 2;
        int c0 = (tid & 3) * 16;
        size_t g = ((size_t)(b * 1024 + t0 + r)) * 1024 + h * 64 + c0;
#pragma unroll
        for (int u = 0; u < 16; u++) sv[(c0 + u) * 65 + r] = v[g + u];
    }
    __syncthreads();
    {
        int d = tid >> 2;
        int tc = (tid & 3) * 16;
        size_t g = ((size_t)(bh * 64 + d)) * 1024 + t0 + tc;
#pragma unroll
        for (int u = 0; u < 16; u++) Vt[g + u] = sv[d * 65 + tc + u];
    }
}

// ---------------------------------------------------------------------------
// Causal flash attention. Block = 64 q-rows (4 waves x 16), 64-key tiles.
// Q pre-scaled by 1/8. Writes attn merged-head layout [b*T+t][h*64+d] bf16.
// ---------------------------------------------------------------------------
__global__ __launch_bounds__(256) void attention(const bf16* Qh, const bf16* Kh,
                                                 const bf16* Vt, bf16* attn) {
    int qblk = blockIdx.x;   // 0..15
    int bh = blockIdx.y;     // 0..63
    int b = bh >> 4, h = bh & 15;
    int wave = threadIdx.x >> 6, lane = threadIdx.x & 63;
    int quad = lane >> 4, l16 = lane & 15;

    const bf16* Qb = Qh + (size_t)bh * 1024 * 64;
    const bf16* Kb = Kh + (size_t)bh * 1024 * 64;
    const bf16* Vb = Vt + (size_t)bh * 64 * 1024;

    __shared__ alignas(16) bf16 sK[64 * 64];
    __shared__ alignas(16) bf16 sV[64 * 64];   // sV[d][key] (transposed V tile)
    __shared__ alignas(16) bf16 sP[4][16 * 64];

    int qrow0 = qblk * 64 + wave * 16;
    bf16x8 aq0 = *(const bf16x8*)&Qb[(size_t)(qrow0 + l16) * 64 + quad * 8];
    bf16x8 aq1 = *(const bf16x8*)&Qb[(size_t)(qrow0 + l16) * 64 + quad * 8 + 32];

    f32x4 o[4];
#pragma unroll
    for (int nt = 0; nt < 4; nt++) o[nt] = (f32x4){0.f, 0.f, 0.f, 0.f};
    float mrow[4], lrow[4];
#pragma unroll
    for (int r = 0; r < 4; r++) { mrow[r] = -3.0e38f; lrow[r] = 0.f; }

    for (int kt = 0; kt <= qblk; ++kt) {
        __syncthreads();
#pragma unroll
        for (int p = 0; p < 2; p++) {
            int rbase = p * 32 + wave * 8;   // 8 rows per wave per pass (128B rows)
            gload_lds16(Kb + (size_t)(kt * 64 + rbase + (lane >> 3)) * 64 + (lane & 7) * 8,
                        &sK[rbase * 64]);
            gload_lds16(Vb + (size_t)(rbase + (lane >> 3)) * 1024 + kt * 64 + (lane & 7) * 8,
                        &sV[rbase * 64]);
        }
        __syncthreads();

        f32x4 S[4];
#pragma unroll
        for (int j = 0; j < 4; j++) {
            bf16x8 bk0 = *(const bf16x8*)&sK[(j * 16 + l16) * 64 + quad * 8];
            bf16x8 bk1 = *(const bf16x8*)&sK[(j * 16 + l16) * 64 + quad * 8 + 32];
            f32x4 z = __builtin_amdgcn_mfma_f32_16x16x32_bf16(aq0, bk0, (f32x4){0.f, 0.f, 0.f, 0.f}, 0, 0, 0);
            S[j] = __builtin_amdgcn_mfma_f32_16x16x32_bf16(aq1, bk1, z, 0, 0, 0);
        }
        if (kt == qblk) {   // diagonal tile: mask key > query
#pragma unroll
            for (int j = 0; j < 4; j++) {
                int key = kt * 64 + j * 16 + l16;
#pragma unroll
                for (int r = 0; r < 4; r++) {
                    int qr = qrow0 + quad * 4 + r;
                    if (key > qr) S[j][r] = -3.0e38f;
                }
            }
        }
        // online softmax (rows live in 16-lane groups sharing `quad`)
        float alpha[4];
#pragma unroll
        for (int r = 0; r < 4; r++) {
            float vmax = fmaxf(fmaxf(S[0][r], S[1][r]), fmaxf(S[2][r], S[3][r]));
            vmax = fmaxf(vmax, __shfl_xor(vmax, 1));
            vmax = fmaxf(vmax, __shfl_xor(vmax, 2));
            vmax = fmaxf(vmax, __shfl_xor(vmax, 4));
            vmax = fmaxf(vmax, __shfl_xor(vmax, 8));
            float mn = fmaxf(mrow[r], vmax);
            alpha[r] = __expf(mrow[r] - mn);
            mrow[r] = mn;
        }
        float rs[4] = {0.f, 0.f, 0.f, 0.f};
#pragma unroll
        for (int j = 0; j < 4; j++)
#pragma unroll
            for (int r = 0; r < 4; r++) {
                float p = __expf(S[j][r] - mrow[r]);
                S[j][r] = p;
                rs[r] += p;
            }
#pragma unroll
        for (int r = 0; r < 4; r++) {
            float v = rs[r];
            v += __shfl_xor(v, 1);
            v += __shfl_xor(v, 2);
            v += __shfl_xor(v, 4);
            v += __shfl_xor(v, 8);
            lrow[r] = lrow[r] * alpha[r] + v;
        }
#pragma unroll
        for (int nt = 0; nt < 4; nt++)
#pragma unroll
            for (int r = 0; r < 4; r++) o[nt][r] *= alpha[r];

        // P: C-layout -> A-layout via per-wave LDS round trip (wave-local, no barrier)
#pragma unroll
        for (int j = 0; j < 4; j++)
#pragma unroll
            for (int r = 0; r < 4; r++)
                sP[wave][(quad * 4 + r) * 64 + j * 16 + l16] = tobf(S[j][r]);
        asm volatile("s_waitcnt lgkmcnt(0)" ::: "memory");
        bf16x8 ap0 = *(const bf16x8*)&sP[wave][l16 * 64 + quad * 8];
        bf16x8 ap1 = *(const bf16x8*)&sP[wave][l16 * 64 + quad * 8 + 32];
#pragma unroll
        for (int nt = 0; nt < 4; nt++) {
            bf16x8 bv0 = *(const bf16x8*)&sV[(nt * 16 + l16) * 64 + quad * 8];
            bf16x8 bv1 = *(const bf16x8*)&sV[(nt * 16 + l16) * 64 + quad * 8 + 32];
            o[nt] = __builtin_amdgcn_mfma_f32_16x16x32_bf16(ap0, bv0, o[nt], 0, 0, 0);
            o[nt] = __builtin_amdgcn_mfma_f32_16x16x32_bf16(ap1, bv1, o[nt], 0, 0, 0);
        }
    }

    float invl[4];
#pragma unroll
    for (int r = 0; r < 4; r++) invl[r] = 1.0f / lrow[r];
#pragma unroll
    for (int nt = 0; nt < 4; nt++)
#pragma unroll
        for (int r = 0; r < 4; r++) {
            int t = qrow0 + quad * 4 + r;
            int col = h * 64 + nt * 16 + l16;
            attn[(size_t)(b * 1024 + t) * 1024 + col] = tobf(o[nt][r] * invl[r]);
        }
}

// ---------------------------------------------------------------------------
extern "C" void kernel_launch(void* const* d_in, const int* in_sizes, int n_in,
                              void* d_out, int out_size, void* d_ws, size_t ws_size,
                              hipStream_t stream) {
    const float* x = (const float*)d_in[0];
    const float* qw = (const float*)d_in[1];
    const float* kw = (const float*)d_in[2];
    const float* vw = (const float*)d_in[3];
    const float* qa = (const float*)d_in[4];
    const float* qb = (const float*)d_in[5];
    const float* ql = (const float*)d_in[6];
    const float* ka = (const float*)d_in[7];
    const float* kb = (const float*)d_in[8];
    const float* kl = (const float*)d_in[9];
    const float* va = (const float*)d_in[10];
    const float* vb = (const float*)d_in[11];
    const float* vl = (const float*)d_in[12];
    const float* pw = (const float*)d_in[13];
    const float* pb = (const float*)d_in[14];
    float* out = (float*)d_out;

    char* ws = (char*)d_ws;
    const size_t MB = 1024 * 1024;
    bf16* wqb = (bf16*)ws;                  // [0,8MB): 4 weight matrices bf16
    bf16* wkb = wqb + 1048576;
    bf16* wvb = wkb + 1048576;
    bf16* wpb = wvb + 1048576;
    bf16* xqb = (bf16*)(ws + 8 * MB);       // [8,32MB): gated inputs
    bf16* xkb = xqb + 4194304;
    bf16* xvb = xkb + 4194304;
    bf16* qm = (bf16*)(ws + 32 * MB);       // [32,56MB): q,k,v GEMM outputs
    bf16* km = qm + 4194304;
    bf16* vm = km + 4194304;
    float* T = (float*)(ws + 32 * MB);      // 768KB, aliases qm head (dead before gemm)
    // aliases (stream-ordered reuse of dead buffers)
    bf16* Qh = xqb;    // rope_transform consumes qm/km/vm, xq* is dead
    bf16* Kh = xkb;
    bf16* Vt = xvb;
    bf16* attn = qm;   // attention consumes Qh/Kh/Vt, qm is dead

    convert_w<<<dim3(1024, 4), 256, 0, stream>>>(qw, kw, vw, pw, wqb);
    lora_t<<<256, 64, 0, stream>>>(x, qa, ka, va, T);
    gate<<<256, 256, 0, stream>>>(x, T, qb, ql, kb, kl, vb, vl, xqb, xkb, xvb);
    gemm128<<<dim3(8, 32, 3), 256, 0, stream>>>(xqb, xkb, xvb, wqb, wkb, wvb, qm, km, vm,
                                                nullptr, nullptr, 0);
    rope_transform<<<dim3(64, 16), 256, 0, stream>>>(qm, km, vm, Qh, Kh, Vt);
    attention<<<dim3(16, 64), 256, 0, stream>>>(Qh, Kh, Vt, attn);
    gemm128<<<dim3(8, 32, 1), 256, 0, stream>>>(attn, nullptr, nullptr, wpb, nullptr, nullptr,
                                                nullptr, nullptr, nullptr, pb, out, 1);
}

// Round 3
// 282.157 us; speedup vs baseline: 1.1609x; 1.1451x over previous
//
#include <hip/hip_runtime.h>
#include <hip/hip_bf16.h>

typedef __hip_bfloat16 bf16;
typedef __attribute__((ext_vector_type(8))) short bf16x8;   // 8 bf16 = 4 VGPRs (MFMA A/B frag)
typedef __attribute__((ext_vector_type(4))) float f32x4;    // MFMA C/D frag

typedef const __attribute__((address_space(1))) unsigned int* gp_t;
typedef __attribute__((address_space(3))) unsigned int* lp_t;

__device__ __forceinline__ bf16 tobf(float f) { return __float2bfloat16(f); }
__device__ __forceinline__ float tof(bf16 h) { return __bfloat162float(h); }

__device__ __forceinline__ short bfbits(float f) {
    bf16 h = __float2bfloat16(f);
    return *reinterpret_cast<short*>(&h);
}
__device__ __forceinline__ bf16x8 pack8(float4 a, float4 b) {
    bf16x8 r;
    r[0] = bfbits(a.x); r[1] = bfbits(a.y); r[2] = bfbits(a.z); r[3] = bfbits(a.w);
    r[4] = bfbits(b.x); r[5] = bfbits(b.y); r[6] = bfbits(b.z); r[7] = bfbits(b.w);
    return r;
}

__device__ __forceinline__ void gload_lds16(const void* g, void* l) {
    // 16B per lane, dest = wave-uniform LDS base + lane*16
    __builtin_amdgcn_global_load_lds((gp_t)g, (lp_t)l, 16, 0, 0);
}

// ---------------------------------------------------------------------------
// Weight fp32 -> bf16 (4 matrices of 1M elements each, contiguous dst)
// ---------------------------------------------------------------------------
__global__ __launch_bounds__(256) void convert_w(const float* qw, const float* kw,
                                                 const float* vw, const float* pw,
                                                 bf16* dst) {
    int m = blockIdx.y;
    const float* src = m == 0 ? qw : (m == 1 ? kw : (m == 2 ? vw : pw));
    bf16* d = dst + (size_t)m * (1u << 20);
    int i = (blockIdx.x * 256 + threadIdx.x) * 4;
    float4 f = *(const float4*)(src + i);
    d[i + 0] = tobf(f.x);
    d[i + 1] = tobf(f.y);
    d[i + 2] = tobf(f.z);
    d[i + 3] = tobf(f.w);
}

// ---------------------------------------------------------------------------
// lora_t: T[row][48] = tanh(x @ a^T) for q,k,v stacked (cols 0-15 q, 16-31 k,
// 32-47 v). One wave per 16-row M-tile, MFMA 16x16x32, operands straight from
// global with in-register fp32->bf16 pack. a matrices (192 KB) are L2-hot.
// ---------------------------------------------------------------------------
__global__ __launch_bounds__(64) void lora_t(const float* x, const float* qa,
                                             const float* ka, const float* va,
                                             float* T) {
    int m0 = blockIdx.x * 16;
    int lane = threadIdx.x;
    int quad = lane >> 4, l16 = lane & 15;

    f32x4 acc[3];
#pragma unroll
    for (int j = 0; j < 3; j++) acc[j] = (f32x4){0.f, 0.f, 0.f, 0.f};

#pragma unroll 4
    for (int k0 = 0; k0 < 1024; k0 += 32) {
        const float* xs = x + (size_t)(m0 + l16) * 1024 + k0 + quad * 8;
        bf16x8 af = pack8(*(const float4*)xs, *(const float4*)(xs + 4));
#pragma unroll
        for (int j = 0; j < 3; ++j) {
            const float* as = (j == 0 ? qa : (j == 1 ? ka : va)) + (size_t)l16 * 1024 + k0 + quad * 8;
            bf16x8 bf_ = pack8(*(const float4*)as, *(const float4*)(as + 4));
            acc[j] = __builtin_amdgcn_mfma_f32_16x16x32_bf16(af, bf_, acc[j], 0, 0, 0);
        }
    }
#pragma unroll
    for (int j = 0; j < 3; ++j)
#pragma unroll
        for (int r = 0; r < 4; ++r) {
            int row = m0 + quad * 4 + r;       // C-layout: row = quad*4+reg, col = l16
            T[(size_t)row * 48 + j * 16 + l16] = tanhf(acc[j][r]);
        }
}

// ---------------------------------------------------------------------------
// gate: xq/xk/xv[row][d] = x + (x_prev - x) * (lam[d] + dot16(T[row], b[d])).
// Block = 16 rows; thread owns 4 d-columns, b-weights in registers, x_prev
// register-carried across the row walk.
// ---------------------------------------------------------------------------
__global__ __launch_bounds__(256) void gate(
    const float* x, const float* T,
    const float* qbw, const float* ql,
    const float* kbw, const float* kl,
    const float* vbw, const float* vl,
    bf16* xqo, bf16* xko, bf16* xvo) {
    int row0 = blockIdx.x * 16;
    int tid = threadIdx.x;
    __shared__ float sT[16][48];
    if (tid < 768) ((float*)sT)[tid] = T[(size_t)row0 * 48 + tid];
    __syncthreads();

#pragma unroll
    for (int u = 0; u < 4; ++u) {
        int d = tid + u * 256;
        float qbv[16], kbv[16], vbv[16];
#pragma unroll
        for (int p = 0; p < 4; ++p) {
            *(float4*)&qbv[p * 4] = *(const float4*)(qbw + (size_t)d * 16 + p * 4);
            *(float4*)&kbv[p * 4] = *(const float4*)(kbw + (size_t)d * 16 + p * 4);
            *(float4*)&vbv[p * 4] = *(const float4*)(vbw + (size_t)d * 16 + p * 4);
        }
        float qlv = ql[d], klv = kl[d], vlv = vl[d];
        float xp = ((row0 & 1023) == 0) ? 0.f : x[(size_t)(row0 - 1) * 1024 + d];
        for (int rr = 0; rr < 16; ++rr) {
            int row = row0 + rr;
            float xc = x[(size_t)row * 1024 + d];
            float dx = xp - xc;
            float gq = qlv, gk = klv, gv = vlv;
#pragma unroll
            for (int j = 0; j < 16; ++j) {
                gq += sT[rr][j] * qbv[j];
                gk += sT[rr][16 + j] * kbv[j];
                gv += sT[rr][32 + j] * vbv[j];
            }
            size_t o = (size_t)row * 1024 + d;
            xqo[o] = tobf(xc + dx * gq);
            xko[o] = tobf(xc + dx * gk);
            xvo[o] = tobf(xc + dx * gv);
            xp = xc;
        }
    }
}

// ---------------------------------------------------------------------------
// m97-style bf16 GEMM: C[m,n] = sum_k A[m,k]*W[n,k] (+bias). K=1024, 128x128 tile.
// mode proj=0: z selects (A,W,C) of q/k/v, bf16 out. proj=1: fp32 out + bias.
// ---------------------------------------------------------------------------
__global__ __launch_bounds__(256) void gemm128(
    const bf16* A0, const bf16* A1, const bf16* A2,
    const bf16* W0, const bf16* W1, const bf16* W2,
    bf16* C0, bf16* C1, bf16* C2,
    const float* bias, float* outF, int proj) {
    const int K = 1024;
    int bz = blockIdx.z;
    const bf16* A = bz == 0 ? A0 : (bz == 1 ? A1 : A2);
    const bf16* W = bz == 0 ? W0 : (bz == 1 ? W1 : W2);
    bf16* C = bz == 0 ? C0 : (bz == 1 ? C1 : C2);
    int m0 = blockIdx.y * 128, n0 = blockIdx.x * 128;

    __shared__ alignas(16) bf16 sA[128 * 32];
    __shared__ alignas(16) bf16 sB[128 * 32];

    int wave = threadIdx.x >> 6, lane = threadIdx.x & 63;
    int quad = lane >> 4, l16 = lane & 15;

    f32x4 acc[4][4];
#pragma unroll
    for (int i = 0; i < 4; i++)
#pragma unroll
        for (int j = 0; j < 4; j++) acc[i][j] = (f32x4){0.f, 0.f, 0.f, 0.f};

    int srow = wave * 16 + (lane >> 2);   // staging row within 64-row pass
    int scol = (lane & 3) * 8;            // staging col (elements)

    for (int k0 = 0; k0 < K; k0 += 32) {
        __syncthreads();
#pragma unroll
        for (int p = 0; p < 2; p++) {
            int row = p * 64 + srow;
            gload_lds16(A + (size_t)(m0 + row) * K + k0 + scol, &sA[(p * 64 + wave * 16) * 32]);
            gload_lds16(W + (size_t)(n0 + row) * K + k0 + scol, &sB[(p * 64 + wave * 16) * 32]);
        }
        __syncthreads();
        int mw = (wave >> 1) * 64, nw = (wave & 1) * 64;
        bf16x8 af[4], bfr[4];
#pragma unroll
        for (int f = 0; f < 4; f++) {
            af[f] = *(const bf16x8*)&sA[(mw + f * 16 + l16) * 32 + quad * 8];
            bfr[f] = *(const bf16x8*)&sB[(nw + f * 16 + l16) * 32 + quad * 8];
        }
#pragma unroll
        for (int i = 0; i < 4; i++)
#pragma unroll
            for (int j = 0; j < 4; j++)
                acc[i][j] = __builtin_amdgcn_mfma_f32_16x16x32_bf16(af[i], bfr[j], acc[i][j], 0, 0, 0);
    }

    int mw = (wave >> 1) * 64, nw = (wave & 1) * 64;
#pragma unroll
    for (int i = 0; i < 4; i++) {
        int mrow = m0 + mw + i * 16 + quad * 4;
#pragma unroll
        for (int j = 0; j < 4; j++) {
            int col = n0 + nw + j * 16 + l16;
            if (proj) {
                float bv = bias[col];
#pragma unroll
                for (int r = 0; r < 4; r++)
                    outF[(size_t)(mrow + r) * 1024 + col] = acc[i][j][r] + bv;
            } else {
#pragma unroll
                for (int r = 0; r < 4; r++)
                    C[(size_t)(mrow + r) * 1024 + col] = tobf(acc[i][j][r]);
            }
        }
    }
}

// ---------------------------------------------------------------------------
// RoPE (q,k) + head-split layout, V transpose. Per block: one (b,h), 64 t-rows.
// Qh,Kh: [bh][t][64] bf16 (Q pre-scaled by 0.125). Vt: [bh][d][T=1024] bf16.
// ---------------------------------------------------------------------------
__global__ __launch_bounds__(256) void rope_transform(
    const bf16* q, const bf16* k, const bf16* v,
    bf16* Qh, bf16* Kh, bf16* Vt) {
    int bh = blockIdx.x, tblk = blockIdx.y;
    int b = bh >> 4, h = bh & 15;
    int t0 = tblk * 64;
    int tid = threadIdx.x;

    int i0 = (tid & 7) * 4;   // rotary index base (0..28)
#pragma unroll
    for (int pp = 0; pp < 2; ++pp) {
        int t = t0 + pp * 32 + (tid >> 3);
        size_t gin = ((size_t)(b * 1024 + t)) * 1024 + h * 64;
        size_t gout = ((size_t)(bh * 1024 + t)) * 64;
        float c[4], s[4];
#pragma unroll
        for (int u = 0; u < 4; ++u) {
            int i = i0 + u;
            float theta = __expf(-(float)i * (9.210340371976184f / 32.0f)); // 10000^(-i/32)
            sincosf((float)t * theta, &s[u], &c[u]);
        }
        float xr[4], xi[4];
#pragma unroll
        for (int u = 0; u < 4; u++) { xr[u] = tof(q[gin + i0 + u]); xi[u] = tof(q[gin + 32 + i0 + u]); }
#pragma unroll
        for (int u = 0; u < 4; u++) {
            Qh[gout + i0 + u]      = tobf((xr[u] * c[u] - xi[u] * s[u]) * 0.125f);
            Qh[gout + 32 + i0 + u] = tobf((xr[u] * s[u] + xi[u] * c[u]) * 0.125f);
        }
#pragma unroll
        for (int u = 0; u < 4; u++) { xr[u] = tof(k[gin + i0 + u]); xi[u] = tof(k[gin + 32 + i0 + u]); }
#pragma unroll
        for (int u = 0; u < 4; u++) {
            Kh[gout + i0 + u]      = tobf(xr[u] * c[u] - xi[u] * s[u]);
            Kh[gout + 32 + i0 + u] = tobf(xr[u] * s[u] + xi[u] * c[u]);
        }
    }

    __shared__ bf16 sv[64 * 65];
    {
        int r = tid >> 2;
        int c0 = (tid & 3) * 16;
        size_t g = ((size_t)(b * 1024 + t0 + r)) * 1024 + h * 64 + c0;
#pragma unroll
        for (int u = 0; u < 16; u++) sv[(c0 + u) * 65 + r] = v[g + u];
    }
    __syncthreads();
    {
        int d = tid >> 2;
        int tc = (tid & 3) * 16;
        size_t g = ((size_t)(bh * 64 + d)) * 1024 + t0 + tc;
#pragma unroll
        for (int u = 0; u < 16; u++) Vt[g + u] = sv[d * 65 + tc + u];
    }
}

// ---------------------------------------------------------------------------
// Causal flash attention. Block = 64 q-rows (4 waves x 16), 64-key tiles.
// Q pre-scaled by 1/8. Writes attn merged-head layout [b*T+t][h*64+d] bf16.
//
// R3: (1) XOR chunk-swizzle on sK/sV/sP: 16B chunk c of row r lives at slot
//     c^(r&7), killing the 16-way bank conflicts of the 128B-row layout
//     (bank group becomes (quad^(l16&7))*4 -> uniform). Staging permutes
//     SOURCE addresses only, so global_load_lds dest stays lane-contiguous.
// (2) Double-buffered K/V, ONE barrier per tile: prefetch kt+1 issued right
//     after the barrier; compiler's vmcnt(0)-before-barrier then drains it
//     exactly one compute-phase later.
// (3) 1D grid: qblk descending (stragglers first), gid%8 = bh&7 pins each
//     bh's 16 q-blocks to one XCD (K/V L2-resident, 2MB/XCD).
// ---------------------------------------------------------------------------
__global__ __launch_bounds__(256) void attention(const bf16* Qh, const bf16* Kh,
                                                 const bf16* Vt, bf16* attn) {
    int gid = blockIdx.x;
    int qblk = 15 - (gid >> 6);
    int bh = (((gid >> 3) & 7) << 3) | (gid & 7);
    int b = bh >> 4, h = bh & 15;
    int wave = threadIdx.x >> 6, lane = threadIdx.x & 63;
    int quad = lane >> 4, l16 = lane & 15;
    int m7 = l16 & 7;

    const bf16* Qb = Qh + (size_t)bh * 1024 * 64;
    const bf16* Kb = Kh + (size_t)bh * 1024 * 64;
    const bf16* Vb = Vt + (size_t)bh * 64 * 1024;

    __shared__ alignas(16) bf16 sK[2][64 * 64];
    __shared__ alignas(16) bf16 sV[2][64 * 64];   // sV[d][key] (transposed V tile)
    __shared__ alignas(16) bf16 sP[4][16 * 64];

    int srow = lane >> 3;                 // row within wave's 8-row staging group
    int scol = ((lane & 7) ^ srow) * 8;   // swizzled source chunk

    auto stage = [&](int kt, int bufi) {
#pragma unroll
        for (int p = 0; p < 2; p++) {
            int rbase = p * 32 + wave * 8;
            gload_lds16(Kb + (size_t)(kt * 64 + rbase + srow) * 64 + scol, &sK[bufi][rbase * 64]);
            gload_lds16(Vb + (size_t)(rbase + srow) * 1024 + kt * 64 + scol, &sV[bufi][rbase * 64]);
        }
    };

    int qrow0 = qblk * 64 + wave * 16;
    bf16x8 aq0 = *(const bf16x8*)&Qb[(size_t)(qrow0 + l16) * 64 + quad * 8];
    bf16x8 aq1 = *(const bf16x8*)&Qb[(size_t)(qrow0 + l16) * 64 + quad * 8 + 32];

    f32x4 o[4];
#pragma unroll
    for (int nt = 0; nt < 4; nt++) o[nt] = (f32x4){0.f, 0.f, 0.f, 0.f};
    float mrow[4], lrow[4];
#pragma unroll
    for (int r = 0; r < 4; r++) { mrow[r] = -3.0e38f; lrow[r] = 0.f; }

    stage(0, 0);

    int buf = 0;
    for (int kt = 0; kt <= qblk; ++kt, buf ^= 1) {
        __syncthreads();   // vmcnt(0) drain: tile kt resident; prior buf reads done
        if (kt < qblk) stage(kt + 1, buf ^ 1);

        f32x4 S[4];
#pragma unroll
        for (int j = 0; j < 4; j++) {
            int row = j * 16 + l16;
            bf16x8 bk0 = *(const bf16x8*)&sK[buf][row * 64 + ((quad ^ m7) * 8)];
            bf16x8 bk1 = *(const bf16x8*)&sK[buf][row * 64 + (((quad + 4) ^ m7) * 8)];
            f32x4 z = __builtin_amdgcn_mfma_f32_16x16x32_bf16(aq0, bk0, (f32x4){0.f, 0.f, 0.f, 0.f}, 0, 0, 0);
            S[j] = __builtin_amdgcn_mfma_f32_16x16x32_bf16(aq1, bk1, z, 0, 0, 0);
        }
        if (kt == qblk) {   // diagonal tile: mask key > query
#pragma unroll
            for (int j = 0; j < 4; j++) {
                int key = kt * 64 + j * 16 + l16;
#pragma unroll
                for (int r = 0; r < 4; r++) {
                    int qr = qrow0 + quad * 4 + r;
                    if (key > qr) S[j][r] = -3.0e38f;
                }
            }
        }
        // online softmax (rows live in 16-lane groups sharing `quad`)
        float alpha[4];
#pragma unroll
        for (int r = 0; r < 4; r++) {
            float vmax = fmaxf(fmaxf(S[0][r], S[1][r]), fmaxf(S[2][r], S[3][r]));
            vmax = fmaxf(vmax, __shfl_xor(vmax, 1));
            vmax = fmaxf(vmax, __shfl_xor(vmax, 2));
            vmax = fmaxf(vmax, __shfl_xor(vmax, 4));
            vmax = fmaxf(vmax, __shfl_xor(vmax, 8));
            float mn = fmaxf(mrow[r], vmax);
            alpha[r] = __expf(mrow[r] - mn);
            mrow[r] = mn;
        }
        float rs[4] = {0.f, 0.f, 0.f, 0.f};
#pragma unroll
        for (int j = 0; j < 4; j++)
#pragma unroll
            for (int r = 0; r < 4; r++) {
                float p = __expf(S[j][r] - mrow[r]);
                S[j][r] = p;
                rs[r] += p;
            }
#pragma unroll
        for (int r = 0; r < 4; r++) {
            float v = rs[r];
            v += __shfl_xor(v, 1);
            v += __shfl_xor(v, 2);
            v += __shfl_xor(v, 4);
            v += __shfl_xor(v, 8);
            lrow[r] = lrow[r] * alpha[r] + v;
        }
#pragma unroll
        for (int nt = 0; nt < 4; nt++)
#pragma unroll
            for (int r = 0; r < 4; r++) o[nt][r] *= alpha[r];

        // P: C-layout -> A-layout via per-wave LDS round trip (wave-local,
        // lgkmcnt-only). Same chunk-swizzle as sK/sV.
#pragma unroll
        for (int j = 0; j < 4; j++) {
            int c = j * 2 + (l16 >> 3);
#pragma unroll
            for (int r = 0; r < 4; r++) {
                int prow = quad * 4 + r;
                sP[wave][prow * 64 + ((c ^ (prow & 7)) * 8) + m7] = tobf(S[j][r]);
            }
        }
        asm volatile("s_waitcnt lgkmcnt(0)" ::: "memory");
        bf16x8 ap0 = *(const bf16x8*)&sP[wave][l16 * 64 + ((quad ^ m7) * 8)];
        bf16x8 ap1 = *(const bf16x8*)&sP[wave][l16 * 64 + (((quad + 4) ^ m7) * 8)];
#pragma unroll
        for (int nt = 0; nt < 4; nt++) {
            int row = nt * 16 + l16;
            bf16x8 bv0 = *(const bf16x8*)&sV[buf][row * 64 + ((quad ^ m7) * 8)];
            bf16x8 bv1 = *(const bf16x8*)&sV[buf][row * 64 + (((quad + 4) ^ m7) * 8)];
            o[nt] = __builtin_amdgcn_mfma_f32_16x16x32_bf16(ap0, bv0, o[nt], 0, 0, 0);
            o[nt] = __builtin_amdgcn_mfma_f32_16x16x32_bf16(ap1, bv1, o[nt], 0, 0, 0);
        }
    }

    float invl[4];
#pragma unroll
    for (int r = 0; r < 4; r++) invl[r] = 1.0f / lrow[r];
#pragma unroll
    for (int nt = 0; nt < 4; nt++)
#pragma unroll
        for (int r = 0; r < 4; r++) {
            int t = qrow0 + quad * 4 + r;
            int col = h * 64 + nt * 16 + l16;
            attn[(size_t)(b * 1024 + t) * 1024 + col] = tobf(o[nt][r] * invl[r]);
        }
}

// ---------------------------------------------------------------------------
extern "C" void kernel_launch(void* const* d_in, const int* in_sizes, int n_in,
                              void* d_out, int out_size, void* d_ws, size_t ws_size,
                              hipStream_t stream) {
    const float* x = (const float*)d_in[0];
    const float* qw = (const float*)d_in[1];
    const float* kw = (const float*)d_in[2];
    const float* vw = (const float*)d_in[3];
    const float* qa = (const float*)d_in[4];
    const float* qb = (const float*)d_in[5];
    const float* ql = (const float*)d_in[6];
    const float* ka = (const float*)d_in[7];
    const float* kb = (const float*)d_in[8];
    const float* kl = (const float*)d_in[9];
    const float* va = (const float*)d_in[10];
    const float* vb = (const float*)d_in[11];
    const float* vl = (const float*)d_in[12];
    const float* pw = (const float*)d_in[13];
    const float* pb = (const float*)d_in[14];
    float* out = (float*)d_out;

    char* ws = (char*)d_ws;
    const size_t MB = 1024 * 1024;
    bf16* wqb = (bf16*)ws;                  // [0,8MB): 4 weight matrices bf16
    bf16* wkb = wqb + 1048576;
    bf16* wvb = wkb + 1048576;
    bf16* wpb = wvb + 1048576;
    bf16* xqb = (bf16*)(ws + 8 * MB);       // [8,32MB): gated inputs
    bf16* xkb = xqb + 4194304;
    bf16* xvb = xkb + 4194304;
    bf16* qm = (bf16*)(ws + 32 * MB);       // [32,56MB): q,k,v GEMM outputs
    bf16* km = qm + 4194304;
    bf16* vm = km + 4194304;
    float* T = (float*)(ws + 32 * MB);      // 768KB, aliases qm head (dead before gemm)
    // aliases (stream-ordered reuse of dead buffers)
    bf16* Qh = xqb;    // rope_transform consumes qm/km/vm, xq* is dead
    bf16* Kh = xkb;
    bf16* Vt = xvb;
    bf16* attn = qm;   // attention consumes Qh/Kh/Vt, qm is dead

    convert_w<<<dim3(1024, 4), 256, 0, stream>>>(qw, kw, vw, pw, wqb);
    lora_t<<<256, 64, 0, stream>>>(x, qa, ka, va, T);
    gate<<<256, 256, 0, stream>>>(x, T, qb, ql, kb, kl, vb, vl, xqb, xkb, xvb);
    gemm128<<<dim3(8, 32, 3), 256, 0, stream>>>(xqb, xkb, xvb, wqb, wkb, wvb, qm, km, vm,
                                                nullptr, nullptr, 0);
    rope_transform<<<dim3(64, 16), 256, 0, stream>>>(qm, km, vm, Qh, Kh, Vt);
    attention<<<1024, 256, 0, stream>>>(Qh, Kh, Vt, attn);
    gemm128<<<dim3(8, 32, 1), 256, 0, stream>>>(attn, nullptr, nullptr, wpb, nullptr, nullptr,
                                                nullptr, nullptr, nullptr, pb, out, 1);
}

// Round 4
// 234.781 us; speedup vs baseline: 1.3951x; 1.2018x over previous
//
#include <hip/hip_runtime.h>
#include <hip/hip_bf16.h>

typedef __hip_bfloat16 bf16;
typedef __attribute__((ext_vector_type(8))) short bf16x8;   // 8 bf16 = 4 VGPRs (MFMA A/B frag)
typedef __attribute__((ext_vector_type(4))) float f32x4;    // MFMA C/D frag

typedef const __attribute__((address_space(1))) unsigned int* gp_t;
typedef __attribute__((address_space(3))) unsigned int* lp_t;

__device__ __forceinline__ bf16 tobf(float f) { return __float2bfloat16(f); }
__device__ __forceinline__ float tof(bf16 h) { return __bfloat162float(h); }

__device__ __forceinline__ short bfbits(float f) {
    bf16 h = __float2bfloat16(f);
    return *reinterpret_cast<short*>(&h);
}
__device__ __forceinline__ bf16x8 pack8(float4 a, float4 b) {
    bf16x8 r;
    r[0] = bfbits(a.x); r[1] = bfbits(a.y); r[2] = bfbits(a.z); r[3] = bfbits(a.w);
    r[4] = bfbits(b.x); r[5] = bfbits(b.y); r[6] = bfbits(b.z); r[7] = bfbits(b.w);
    return r;
}

__device__ __forceinline__ void gload_lds16(const void* g, void* l) {
    // 16B per lane, dest = wave-uniform LDS base + lane*16
    __builtin_amdgcn_global_load_lds((gp_t)g, (lp_t)l, 16, 0, 0);
}

// ---------------------------------------------------------------------------
// Weight fp32 -> bf16 (4 matrices of 1M elements each, contiguous dst)
// ---------------------------------------------------------------------------
__global__ __launch_bounds__(256) void convert_w(const float* qw, const float* kw,
                                                 const float* vw, const float* pw,
                                                 bf16* dst) {
    int m = blockIdx.y;
    const float* src = m == 0 ? qw : (m == 1 ? kw : (m == 2 ? vw : pw));
    bf16* d = dst + (size_t)m * (1u << 20);
    int i = (blockIdx.x * 256 + threadIdx.x) * 4;
    float4 f = *(const float4*)(src + i);
    d[i + 0] = tobf(f.x);
    d[i + 1] = tobf(f.y);
    d[i + 2] = tobf(f.z);
    d[i + 3] = tobf(f.w);
}

// ---------------------------------------------------------------------------
// Fused LoRA gate (R4): one block = 16 rows.
//   phase 0: stage x rows [row0-1, row0+16) into LDS (stride 1028 floats:
//            +16B pad per row -> phase-1 frag reads are 2-way on banks = free,
//            and every global_load_lds dest chunk stays 16B-aligned).
//   phase 1: waves 0-2 compute T(16x16) = tanh(x @ a^T) for q/k/v via MFMA
//            (A from LDS-x packed to bf16, B = a-rows from global, L2-hot).
//   phase 2: all waves: xq/xk/xv = x + (x_prev - x)*(lam + T.b^T), bf16 out,
//            x read from LDS, b-weights in registers, x_prev reg-carried.
// Replaces lora_t (1 wave/CU, latency-bound, 50-67us) + gate.
// ---------------------------------------------------------------------------
__global__ __launch_bounds__(256) void lora_gate_fused(
    const float* x,
    const float* qa, const float* ka, const float* va,
    const float* qbw, const float* ql,
    const float* kbw, const float* kl,
    const float* vbw, const float* vl,
    bf16* xqo, bf16* xko, bf16* xvo) {
    const int XS = 1028;                    // padded row stride (floats)
    int row0 = blockIdx.x * 16;
    int t0 = row0 & 1023;
    int tid = threadIdx.x;
    int wave = tid >> 6, lane = tid & 63;
    int quad = lane >> 4, l16 = lane & 15;

    __shared__ float sx[17 * 1028];
    __shared__ float sT[16 * 48];

    // phase 0: stage 17 rows; wave w stages quarter-row chunk w (1 KB each)
    {
        int prow = (row0 == 0) ? 0 : row0 - 1;   // clamped; value unused when t0==0
        for (int i = 0; i < 17; ++i) {
            int grow = (i == 0) ? prow : row0 + i - 1;
            gload_lds16(x + (size_t)grow * 1024 + wave * 256 + lane * 4,
                        &sx[i * XS + wave * 256]);
        }
    }
    __syncthreads();

    // phase 1: waves 0-2 -> T tiles
    if (wave < 3) {
        const float* am = wave == 0 ? qa : (wave == 1 ? ka : va);
        f32x4 acc = (f32x4){0.f, 0.f, 0.f, 0.f};
#pragma unroll 4
        for (int k0 = 0; k0 < 1024; k0 += 32) {
            const float* xs = &sx[(1 + l16) * XS + k0 + quad * 8];
            bf16x8 af = pack8(*(const float4*)xs, *(const float4*)(xs + 4));
            const float* as = am + (size_t)l16 * 1024 + k0 + quad * 8;
            bf16x8 bf_ = pack8(*(const float4*)as, *(const float4*)(as + 4));
            acc = __builtin_amdgcn_mfma_f32_16x16x32_bf16(af, bf_, acc, 0, 0, 0);
        }
#pragma unroll
        for (int r = 0; r < 4; ++r)
            sT[(quad * 4 + r) * 48 + wave * 16 + l16] = tanhf(acc[r]);
    }
    __syncthreads();

    // phase 2: gate
#pragma unroll
    for (int u = 0; u < 4; ++u) {
        int d = tid + u * 256;
        float qbv[16], kbv[16], vbv[16];
#pragma unroll
        for (int p = 0; p < 4; ++p) {
            *(float4*)&qbv[p * 4] = *(const float4*)(qbw + (size_t)d * 16 + p * 4);
            *(float4*)&kbv[p * 4] = *(const float4*)(kbw + (size_t)d * 16 + p * 4);
            *(float4*)&vbv[p * 4] = *(const float4*)(vbw + (size_t)d * 16 + p * 4);
        }
        float qlv = ql[d], klv = kl[d], vlv = vl[d];
        float xp = (t0 == 0) ? 0.f : sx[0 * XS + d];
        for (int rr = 0; rr < 16; ++rr) {
            float xc = sx[(rr + 1) * XS + d];
            float dx = xp - xc;
            float gq = qlv, gk = klv, gv = vlv;
#pragma unroll
            for (int j = 0; j < 16; ++j) {
                gq += sT[rr * 48 + j] * qbv[j];
                gk += sT[rr * 48 + 16 + j] * kbv[j];
                gv += sT[rr * 48 + 32 + j] * vbv[j];
            }
            size_t o = (size_t)(row0 + rr) * 1024 + d;
            xqo[o] = tobf(xc + dx * gq);
            xko[o] = tobf(xc + dx * gk);
            xvo[o] = tobf(xc + dx * gv);
            xp = xc;
        }
    }
}

// ---------------------------------------------------------------------------
// m97-style bf16 GEMM: C[m,n] = sum_k A[m,k]*W[n,k] (+bias). K=1024, 128x128 tile.
// mode proj=0: z selects (A,W,C) of q/k/v, bf16 out. proj=1: fp32 out + bias.
// ---------------------------------------------------------------------------
__global__ __launch_bounds__(256) void gemm128(
    const bf16* A0, const bf16* A1, const bf16* A2,
    const bf16* W0, const bf16* W1, const bf16* W2,
    bf16* C0, bf16* C1, bf16* C2,
    const float* bias, float* outF, int proj) {
    const int K = 1024;
    int bz = blockIdx.z;
    const bf16* A = bz == 0 ? A0 : (bz == 1 ? A1 : A2);
    const bf16* W = bz == 0 ? W0 : (bz == 1 ? W1 : W2);
    bf16* C = bz == 0 ? C0 : (bz == 1 ? C1 : C2);
    int m0 = blockIdx.y * 128, n0 = blockIdx.x * 128;

    __shared__ alignas(16) bf16 sA[128 * 32];
    __shared__ alignas(16) bf16 sB[128 * 32];

    int wave = threadIdx.x >> 6, lane = threadIdx.x & 63;
    int quad = lane >> 4, l16 = lane & 15;

    f32x4 acc[4][4];
#pragma unroll
    for (int i = 0; i < 4; i++)
#pragma unroll
        for (int j = 0; j < 4; j++) acc[i][j] = (f32x4){0.f, 0.f, 0.f, 0.f};

    int srow = wave * 16 + (lane >> 2);   // staging row within 64-row pass
    int scol = (lane & 3) * 8;            // staging col (elements)

    for (int k0 = 0; k0 < K; k0 += 32) {
        __syncthreads();
#pragma unroll
        for (int p = 0; p < 2; p++) {
            int row = p * 64 + srow;
            gload_lds16(A + (size_t)(m0 + row) * K + k0 + scol, &sA[(p * 64 + wave * 16) * 32]);
            gload_lds16(W + (size_t)(n0 + row) * K + k0 + scol, &sB[(p * 64 + wave * 16) * 32]);
        }
        __syncthreads();
        int mw = (wave >> 1) * 64, nw = (wave & 1) * 64;
        bf16x8 af[4], bfr[4];
#pragma unroll
        for (int f = 0; f < 4; f++) {
            af[f] = *(const bf16x8*)&sA[(mw + f * 16 + l16) * 32 + quad * 8];
            bfr[f] = *(const bf16x8*)&sB[(nw + f * 16 + l16) * 32 + quad * 8];
        }
#pragma unroll
        for (int i = 0; i < 4; i++)
#pragma unroll
            for (int j = 0; j < 4; j++)
                acc[i][j] = __builtin_amdgcn_mfma_f32_16x16x32_bf16(af[i], bfr[j], acc[i][j], 0, 0, 0);
    }

    int mw = (wave >> 1) * 64, nw = (wave & 1) * 64;
#pragma unroll
    for (int i = 0; i < 4; i++) {
        int mrow = m0 + mw + i * 16 + quad * 4;
#pragma unroll
        for (int j = 0; j < 4; j++) {
            int col = n0 + nw + j * 16 + l16;
            if (proj) {
                float bv = bias[col];
#pragma unroll
                for (int r = 0; r < 4; r++)
                    outF[(size_t)(mrow + r) * 1024 + col] = acc[i][j][r] + bv;
            } else {
#pragma unroll
                for (int r = 0; r < 4; r++)
                    C[(size_t)(mrow + r) * 1024 + col] = tobf(acc[i][j][r]);
            }
        }
    }
}

// ---------------------------------------------------------------------------
// RoPE (q,k) + head-split layout, V transpose. Per block: one (b,h), 64 t-rows.
// Qh,Kh: [bh][t][64] bf16 (Q pre-scaled by 0.125). Vt: [bh][d][T=1024] bf16.
// ---------------------------------------------------------------------------
__global__ __launch_bounds__(256) void rope_transform(
    const bf16* q, const bf16* k, const bf16* v,
    bf16* Qh, bf16* Kh, bf16* Vt) {
    int bh = blockIdx.x, tblk = blockIdx.y;
    int b = bh >> 4, h = bh & 15;
    int t0 = tblk * 64;
    int tid = threadIdx.x;

    int i0 = (tid & 7) * 4;   // rotary index base (0..28)
#pragma unroll
    for (int pp = 0; pp < 2; ++pp) {
        int t = t0 + pp * 32 + (tid >> 3);
        size_t gin = ((size_t)(b * 1024 + t)) * 1024 + h * 64;
        size_t gout = ((size_t)(bh * 1024 + t)) * 64;
        float c[4], s[4];
#pragma unroll
        for (int u = 0; u < 4; ++u) {
            int i = i0 + u;
            float theta = __expf(-(float)i * (9.210340371976184f / 32.0f)); // 10000^(-i/32)
            sincosf((float)t * theta, &s[u], &c[u]);
        }
        float xr[4], xi[4];
#pragma unroll
        for (int u = 0; u < 4; u++) { xr[u] = tof(q[gin + i0 + u]); xi[u] = tof(q[gin + 32 + i0 + u]); }
#pragma unroll
        for (int u = 0; u < 4; u++) {
            Qh[gout + i0 + u]      = tobf((xr[u] * c[u] - xi[u] * s[u]) * 0.125f);
            Qh[gout + 32 + i0 + u] = tobf((xr[u] * s[u] + xi[u] * c[u]) * 0.125f);
        }
#pragma unroll
        for (int u = 0; u < 4; u++) { xr[u] = tof(k[gin + i0 + u]); xi[u] = tof(k[gin + 32 + i0 + u]); }
#pragma unroll
        for (int u = 0; u < 4; u++) {
            Kh[gout + i0 + u]      = tobf(xr[u] * c[u] - xi[u] * s[u]);
            Kh[gout + 32 + i0 + u] = tobf(xr[u] * s[u] + xi[u] * c[u]);
        }
    }

    __shared__ bf16 sv[64 * 65];
    {
        int r = tid >> 2;
        int c0 = (tid & 3) * 16;
        size_t g = ((size_t)(b * 1024 + t0 + r)) * 1024 + h * 64 + c0;
#pragma unroll
        for (int u = 0; u < 16; u++) sv[(c0 + u) * 65 + r] = v[g + u];
    }
    __syncthreads();
    {
        int d = tid >> 2;
        int tc = (tid & 3) * 16;
        size_t g = ((size_t)(bh * 64 + d)) * 1024 + t0 + tc;
#pragma unroll
        for (int u = 0; u < 16; u++) Vt[g + u] = sv[d * 65 + tc + u];
    }
}

// ---------------------------------------------------------------------------
// Causal flash attention. Block = 64 q-rows (4 waves x 16), 64-key tiles.
// Q pre-scaled by 1/8. Writes attn merged-head layout [b*T+t][h*64+d] bf16.
// XOR chunk-swizzle on sK/sV/sP; double-buffered K/V, one barrier per tile;
// 1D grid: qblk descending, gid%8 pins bh to one XCD for K/V L2 residency.
// ---------------------------------------------------------------------------
__global__ __launch_bounds__(256) void attention(const bf16* Qh, const bf16* Kh,
                                                 const bf16* Vt, bf16* attn) {
    int gid = blockIdx.x;
    int qblk = 15 - (gid >> 6);
    int bh = (((gid >> 3) & 7) << 3) | (gid & 7);
    int b = bh >> 4, h = bh & 15;
    int wave = threadIdx.x >> 6, lane = threadIdx.x & 63;
    int quad = lane >> 4, l16 = lane & 15;
    int m7 = l16 & 7;

    const bf16* Qb = Qh + (size_t)bh * 1024 * 64;
    const bf16* Kb = Kh + (size_t)bh * 1024 * 64;
    const bf16* Vb = Vt + (size_t)bh * 64 * 1024;

    __shared__ alignas(16) bf16 sK[2][64 * 64];
    __shared__ alignas(16) bf16 sV[2][64 * 64];   // sV[d][key] (transposed V tile)
    __shared__ alignas(16) bf16 sP[4][16 * 64];

    int srow = lane >> 3;                 // row within wave's 8-row staging group
    int scol = ((lane & 7) ^ srow) * 8;   // swizzled source chunk

    auto stage = [&](int kt, int bufi) {
#pragma unroll
        for (int p = 0; p < 2; p++) {
            int rbase = p * 32 + wave * 8;
            gload_lds16(Kb + (size_t)(kt * 64 + rbase + srow) * 64 + scol, &sK[bufi][rbase * 64]);
            gload_lds16(Vb + (size_t)(rbase + srow) * 1024 + kt * 64 + scol, &sV[bufi][rbase * 64]);
        }
    };

    int qrow0 = qblk * 64 + wave * 16;
    bf16x8 aq0 = *(const bf16x8*)&Qb[(size_t)(qrow0 + l16) * 64 + quad * 8];
    bf16x8 aq1 = *(const bf16x8*)&Qb[(size_t)(qrow0 + l16) * 64 + quad * 8 + 32];

    f32x4 o[4];
#pragma unroll
    for (int nt = 0; nt < 4; nt++) o[nt] = (f32x4){0.f, 0.f, 0.f, 0.f};
    float mrow[4], lrow[4];
#pragma unroll
    for (int r = 0; r < 4; r++) { mrow[r] = -3.0e38f; lrow[r] = 0.f; }

    stage(0, 0);

    int buf = 0;
    for (int kt = 0; kt <= qblk; ++kt, buf ^= 1) {
        __syncthreads();   // vmcnt(0) drain: tile kt resident; prior buf reads done
        if (kt < qblk) stage(kt + 1, buf ^ 1);

        f32x4 S[4];
#pragma unroll
        for (int j = 0; j < 4; j++) {
            int row = j * 16 + l16;
            bf16x8 bk0 = *(const bf16x8*)&sK[buf][row * 64 + ((quad ^ m7) * 8)];
            bf16x8 bk1 = *(const bf16x8*)&sK[buf][row * 64 + (((quad + 4) ^ m7) * 8)];
            f32x4 z = __builtin_amdgcn_mfma_f32_16x16x32_bf16(aq0, bk0, (f32x4){0.f, 0.f, 0.f, 0.f}, 0, 0, 0);
            S[j] = __builtin_amdgcn_mfma_f32_16x16x32_bf16(aq1, bk1, z, 0, 0, 0);
        }
        if (kt == qblk) {   // diagonal tile: mask key > query
#pragma unroll
            for (int j = 0; j < 4; j++) {
                int key = kt * 64 + j * 16 + l16;
#pragma unroll
                for (int r = 0; r < 4; r++) {
                    int qr = qrow0 + quad * 4 + r;
                    if (key > qr) S[j][r] = -3.0e38f;
                }
            }
        }
        // online softmax (rows live in 16-lane groups sharing `quad`)
        float alpha[4];
#pragma unroll
        for (int r = 0; r < 4; r++) {
            float vmax = fmaxf(fmaxf(S[0][r], S[1][r]), fmaxf(S[2][r], S[3][r]));
            vmax = fmaxf(vmax, __shfl_xor(vmax, 1));
            vmax = fmaxf(vmax, __shfl_xor(vmax, 2));
            vmax = fmaxf(vmax, __shfl_xor(vmax, 4));
            vmax = fmaxf(vmax, __shfl_xor(vmax, 8));
            float mn = fmaxf(mrow[r], vmax);
            alpha[r] = __expf(mrow[r] - mn);
            mrow[r] = mn;
        }
        float rs[4] = {0.f, 0.f, 0.f, 0.f};
#pragma unroll
        for (int j = 0; j < 4; j++)
#pragma unroll
            for (int r = 0; r < 4; r++) {
                float p = __expf(S[j][r] - mrow[r]);
                S[j][r] = p;
                rs[r] += p;
            }
#pragma unroll
        for (int r = 0; r < 4; r++) {
            float v = rs[r];
            v += __shfl_xor(v, 1);
            v += __shfl_xor(v, 2);
            v += __shfl_xor(v, 4);
            v += __shfl_xor(v, 8);
            lrow[r] = lrow[r] * alpha[r] + v;
        }
#pragma unroll
        for (int nt = 0; nt < 4; nt++)
#pragma unroll
            for (int r = 0; r < 4; r++) o[nt][r] *= alpha[r];

        // P: C-layout -> A-layout via per-wave LDS round trip (wave-local,
        // lgkmcnt-only). Same chunk-swizzle as sK/sV.
#pragma unroll
        for (int j = 0; j < 4; j++) {
            int c = j * 2 + (l16 >> 3);
#pragma unroll
            for (int r = 0; r < 4; r++) {
                int prow = quad * 4 + r;
                sP[wave][prow * 64 + ((c ^ (prow & 7)) * 8) + m7] = tobf(S[j][r]);
            }
        }
        asm volatile("s_waitcnt lgkmcnt(0)" ::: "memory");
        bf16x8 ap0 = *(const bf16x8*)&sP[wave][l16 * 64 + ((quad ^ m7) * 8)];
        bf16x8 ap1 = *(const bf16x8*)&sP[wave][l16 * 64 + (((quad + 4) ^ m7) * 8)];
#pragma unroll
        for (int nt = 0; nt < 4; nt++) {
            int row = nt * 16 + l16;
            bf16x8 bv0 = *(const bf16x8*)&sV[buf][row * 64 + ((quad ^ m7) * 8)];
            bf16x8 bv1 = *(const bf16x8*)&sV[buf][row * 64 + (((quad + 4) ^ m7) * 8)];
            o[nt] = __builtin_amdgcn_mfma_f32_16x16x32_bf16(ap0, bv0, o[nt], 0, 0, 0);
            o[nt] = __builtin_amdgcn_mfma_f32_16x16x32_bf16(ap1, bv1, o[nt], 0, 0, 0);
        }
    }

    float invl[4];
#pragma unroll
    for (int r = 0; r < 4; r++) invl[r] = 1.0f / lrow[r];
#pragma unroll
    for (int nt = 0; nt < 4; nt++)
#pragma unroll
        for (int r = 0; r < 4; r++) {
            int t = qrow0 + quad * 4 + r;
            int col = h * 64 + nt * 16 + l16;
            attn[(size_t)(b * 1024 + t) * 1024 + col] = tobf(o[nt][r] * invl[r]);
        }
}

// ---------------------------------------------------------------------------
extern "C" void kernel_launch(void* const* d_in, const int* in_sizes, int n_in,
                              void* d_out, int out_size, void* d_ws, size_t ws_size,
                              hipStream_t stream) {
    const float* x = (const float*)d_in[0];
    const float* qw = (const float*)d_in[1];
    const float* kw = (const float*)d_in[2];
    const float* vw = (const float*)d_in[3];
    const float* qa = (const float*)d_in[4];
    const float* qb = (const float*)d_in[5];
    const float* ql = (const float*)d_in[6];
    const float* ka = (const float*)d_in[7];
    const float* kb = (const float*)d_in[8];
    const float* kl = (const float*)d_in[9];
    const float* va = (const float*)d_in[10];
    const float* vb = (const float*)d_in[11];
    const float* vl = (const float*)d_in[12];
    const float* pw = (const float*)d_in[13];
    const float* pb = (const float*)d_in[14];
    float* out = (float*)d_out;

    char* ws = (char*)d_ws;
    const size_t MB = 1024 * 1024;
    bf16* wqb = (bf16*)ws;                  // [0,8MB): 4 weight matrices bf16
    bf16* wkb = wqb + 1048576;
    bf16* wvb = wkb + 1048576;
    bf16* wpb = wvb + 1048576;
    bf16* xqb = (bf16*)(ws + 8 * MB);       // [8,32MB): gated inputs
    bf16* xkb = xqb + 4194304;
    bf16* xvb = xkb + 4194304;
    bf16* qm = (bf16*)(ws + 32 * MB);       // [32,56MB): q,k,v GEMM outputs
    bf16* km = qm + 4194304;
    bf16* vm = km + 4194304;
    // aliases (stream-ordered reuse of dead buffers)
    bf16* Qh = xqb;    // rope_transform consumes qm/km/vm, xq* is dead
    bf16* Kh = xkb;
    bf16* Vt = xvb;
    bf16* attn = qm;   // attention consumes Qh/Kh/Vt, qm is dead

    convert_w<<<dim3(1024, 4), 256, 0, stream>>>(qw, kw, vw, pw, wqb);
    lora_gate_fused<<<256, 256, 0, stream>>>(x, qa, ka, va, qb, ql, kb, kl, vb, vl,
                                             xqb, xkb, xvb);
    gemm128<<<dim3(8, 32, 3), 256, 0, stream>>>(xqb, xkb, xvb, wqb, wkb, wvb, qm, km, vm,
                                                nullptr, nullptr, 0);
    rope_transform<<<dim3(64, 16), 256, 0, stream>>>(qm, km, vm, Qh, Kh, Vt);
    attention<<<1024, 256, 0, stream>>>(Qh, Kh, Vt, attn);
    gemm128<<<dim3(8, 32, 1), 256, 0, stream>>>(attn, nullptr, nullptr, wpb, nullptr, nullptr,
                                                nullptr, nullptr, nullptr, pb, out, 1);
}